// Round 1
// baseline (76.958 us; speedup 1.0000x reference)
//
#include <hip/hip_runtime.h>
#include <hip/hip_bf16.h>

// RaggedMoEScatter:
//   inputs (setup_inputs order):
//     d_in[0] expert_cumsum  int32 [8]
//     d_in[1] mapped_slots   int32 [16384, 2]
//     d_in[2] activations    f32   [16384, 2048]
//     d_in[3] expert_counts  int32 [8]
//     d_in[4] assignments    int32 [16384, 2]
//     d_in[5] offsets        int32 [16384, 2]
//   output (flat float32, concatenated):
//     moe_input     f32 [8*4096, 2048]  = 67108864 elems
//     expert_cumsum (as float values)   = 8 elems
//     mapped_slots  (as float values)   = 32768 elems

#define N_TOKENS 16384
#define TOP_K    2
#define N_EXPERTS 8
#define HIDDEN   2048
#define CAPACITY 4096                       // N_TOKENS*TOP_K/N_EXPERTS
#define MOE_ELEMS ((size_t)N_EXPERTS * CAPACITY * HIDDEN)
#define VEC_PER_ROW (HIDDEN / 4)            // 512 float4 per row

__global__ __launch_bounds__(256) void moe_scatter_kernel(
    const float* __restrict__ acts,      // [N_TOKENS, HIDDEN]
    const int*   __restrict__ slots,     // [N_TOKENS, TOP_K]
    const int*   __restrict__ cumsum,    // [N_EXPERTS]
    float*       __restrict__ out)       // [MOE_ELEMS + 8 + 32768]
{
    const int b = blockIdx.x;

    if (b < N_TOKENS) {
        // One block per token: read the row once, write it to TOP_K slot rows.
        const int s0 = slots[b * TOP_K + 0];
        const int s1 = slots[b * TOP_K + 1];

        const float4* __restrict__ src =
            reinterpret_cast<const float4*>(acts + (size_t)b * HIDDEN);
        float4* __restrict__ dst0 =
            reinterpret_cast<float4*>(out + (size_t)s0 * HIDDEN);
        float4* __restrict__ dst1 =
            reinterpret_cast<float4*>(out + (size_t)s1 * HIDDEN);

        // 512 float4 per row, 256 threads -> 2 iterations, fully coalesced.
        #pragma unroll
        for (int i = threadIdx.x; i < VEC_PER_ROW; i += 256) {
            float4 v = src[i];
            dst0[i] = v;
            dst1[i] = v;
        }
    } else {
        // Tail blocks: write the two small pass-through outputs as float values.
        const int i = (b - N_TOKENS) * 256 + threadIdx.x;
        float* tail = out + MOE_ELEMS;
        if (i < N_EXPERTS) {
            tail[i] = (float)cumsum[i];
        }
        if (i < N_TOKENS * TOP_K) {
            tail[N_EXPERTS + i] = (float)slots[i];
        }
    }
}

extern "C" void kernel_launch(void* const* d_in, const int* in_sizes, int n_in,
                              void* d_out, int out_size, void* d_ws, size_t ws_size,
                              hipStream_t stream) {
    const int*   expert_cumsum = (const int*)d_in[0];
    const int*   mapped_slots  = (const int*)d_in[1];
    const float* activations   = (const float*)d_in[2];
    float*       out           = (float*)d_out;

    // 16384 scatter blocks + 128 tail blocks (32768 pass-through ints / 256)
    const int tail_blocks = (N_TOKENS * TOP_K + 255) / 256;
    dim3 grid(N_TOKENS + tail_blocks);
    dim3 block(256);
    moe_scatter_kernel<<<grid, block, 0, stream>>>(activations, mapped_slots,
                                                   expert_cumsum, out);
}

// Round 3
// 64.367 us; speedup vs baseline: 1.1956x; 1.1956x over previous
//
#include <hip/hip_runtime.h>
#include <hip/hip_bf16.h>

// RaggedMoEScatter:
//   inputs (setup_inputs order):
//     d_in[0] expert_cumsum  int32 [8]
//     d_in[1] mapped_slots   int32 [16384, 2]
//     d_in[2] activations    f32   [16384, 2048]
//     d_in[3] expert_counts  int32 [8]
//     d_in[4] assignments    int32 [16384, 2]
//     d_in[5] offsets        int32 [16384, 2]
//   output (flat float32, concatenated):
//     moe_input     f32 [8*4096, 2048]  = 67108864 elems
//     expert_cumsum (as float values)   = 8 elems
//     mapped_slots  (as float values)   = 32768 elems

#define N_TOKENS 16384
#define TOP_K    2
#define N_EXPERTS 8
#define HIDDEN   2048
#define CAPACITY 4096                       // N_TOKENS*TOP_K/N_EXPERTS
#define MOE_ELEMS ((size_t)N_EXPERTS * CAPACITY * HIDDEN)
#define VEC_PER_ROW (HIDDEN / 4)            // 512 float4 per row
#define SCATTER_BLOCKS 2048                 // 8 blocks/CU, 8 tokens per block

// Clang-native vector type: __builtin_nontemporal_store accepts this
// (it rejects HIP's struct-wrapped float4).
typedef float f32x4 __attribute__((ext_vector_type(4)));

__global__ __launch_bounds__(256) void moe_scatter_kernel(
    const float* __restrict__ acts,      // [N_TOKENS, HIDDEN]
    const int*   __restrict__ slots,     // [N_TOKENS, TOP_K]
    const int*   __restrict__ cumsum,    // [N_EXPERTS]
    float*       __restrict__ out)       // [MOE_ELEMS + 8 + 32768]
{
    const int b = blockIdx.x;

    if (b < SCATTER_BLOCKS) {
        // Grid-stride over tokens: each block handles N_TOKENS/SCATTER_BLOCKS = 8
        // tokens. Reads are cached (L3 can retain the 134 MB activation stream
        // across replays); writes are non-temporal (write-once stream, don't
        // pollute L2/L3).
        for (int t = b; t < N_TOKENS; t += SCATTER_BLOCKS) {
            const int s0 = slots[t * TOP_K + 0];
            const int s1 = slots[t * TOP_K + 1];

            const f32x4* __restrict__ src =
                reinterpret_cast<const f32x4*>(acts + (size_t)t * HIDDEN);
            f32x4* __restrict__ dst0 =
                reinterpret_cast<f32x4*>(out + (size_t)s0 * HIDDEN);
            f32x4* __restrict__ dst1 =
                reinterpret_cast<f32x4*>(out + (size_t)s1 * HIDDEN);

            #pragma unroll
            for (int i = threadIdx.x; i < VEC_PER_ROW; i += 256) {
                f32x4 v = src[i];
                __builtin_nontemporal_store(v, &dst0[i]);
                __builtin_nontemporal_store(v, &dst1[i]);
            }
        }
    } else {
        // Tail blocks: write the two small pass-through outputs as float values.
        const int i = (b - SCATTER_BLOCKS) * 256 + threadIdx.x;
        float* tail = out + MOE_ELEMS;
        if (i < N_EXPERTS) {
            tail[i] = (float)cumsum[i];
        }
        if (i < N_TOKENS * TOP_K) {
            tail[N_EXPERTS + i] = (float)slots[i];
        }
    }
}

extern "C" void kernel_launch(void* const* d_in, const int* in_sizes, int n_in,
                              void* d_out, int out_size, void* d_ws, size_t ws_size,
                              hipStream_t stream) {
    const int*   expert_cumsum = (const int*)d_in[0];
    const int*   mapped_slots  = (const int*)d_in[1];
    const float* activations   = (const float*)d_in[2];
    float*       out           = (float*)d_out;

    const int tail_blocks = (N_TOKENS * TOP_K + 255) / 256;  // 128
    dim3 grid(SCATTER_BLOCKS + tail_blocks);
    dim3 block(256);
    moe_scatter_kernel<<<grid, block, 0, stream>>>(activations, mapped_slots,
                                                   expert_cumsum, out);
}